// Round 4
// baseline (171.545 us; speedup 1.0000x reference)
//
#include <hip/hip_runtime.h>
#include <hip/hip_bf16.h>

typedef short short8 __attribute__((ext_vector_type(8)));   // 8 bf16 = 4 VGPRs
typedef float f32x4 __attribute__((ext_vector_type(4)));
typedef unsigned short u16;

__device__ __forceinline__ unsigned short f2bf(float f) {
  unsigned int u = __float_as_uint(f);
  u += 0x7fffu + ((u >> 16) & 1u);    // round-to-nearest-even
  return (unsigned short)(u >> 16);
}

// async 16B global->LDS (dest = wave-uniform base + lane*16)
__device__ __forceinline__ void glds16(const void* g, void* l) {
  __builtin_amdgcn_global_load_lds(
      (const __attribute__((address_space(1))) unsigned int*)g,
      (__attribute__((address_space(3))) unsigned int*)l, 16, 0, 0);
}

// ---- fused: cast q/m -> bf16, cast wq*(1/(8 ln2)) -> bf16, cast wk, zero out ----
__global__ __launch_bounds__(256) void prep(const float4* __restrict__ q,
                                            const float4* __restrict__ m,
                                            const float4* __restrict__ wq,
                                            const float4* __restrict__ wk,
                                            ushort4* __restrict__ qb,
                                            ushort4* __restrict__ mb,
                                            ushort4* __restrict__ wqb,
                                            ushort4* __restrict__ wkb,
                                            float4* __restrict__ out0) {
  const int i = blockIdx.x * 256 + threadIdx.x;
  const float c = 0.18033688011112042f;  // 1/(8*ln2): folds SCALE and exp->exp2
  if (i < 1048576) {
    float4 v = q[i];
    ushort4 o; o.x = f2bf(v.x); o.y = f2bf(v.y); o.z = f2bf(v.z); o.w = f2bf(v.w);
    qb[i] = o;
  } else if (i < 2097152) {
    float4 v = m[i - 1048576];
    ushort4 o; o.x = f2bf(v.x); o.y = f2bf(v.y); o.z = f2bf(v.z); o.w = f2bf(v.w);
    mb[i - 1048576] = o;
  } else if (i < 2359296) {
    float4 v = wq[i - 2097152];
    ushort4 o; o.x = f2bf(v.x * c); o.y = f2bf(v.y * c); o.z = f2bf(v.z * c); o.w = f2bf(v.w * c);
    wqb[i - 2097152] = o;
  } else if (i < 2621440) {
    float4 v = wk[i - 2359296];
    ushort4 o; o.x = f2bf(v.x); o.y = f2bf(v.y); o.z = f2bf(v.z); o.w = f2bf(v.w);
    wkb[i - 2359296] = o;
  } else if (i < 2637824) {
    out0[i - 2621440] = (float4){0.f, 0.f, 0.f, 0.f};  // zero 65536-float output
  }
}

// ---- C = A[M,1024] @ B[N,1024]^T, 128x128 tile, BK=64, 512 thr (8 waves),
// double-buffered LDS (1 barrier/iter). Epilogue scatters bf16 directly into
// MFMA fragment layout: F[(bt*16+h)*32+t16][half][fragLane][j],
// fragment = A[m=lane&15][k=quad*8+j] (m,k within 16x32 half-tile).
__global__ __launch_bounds__(512) void gemm_frag(const u16* __restrict__ A0,
                                                 const u16* __restrict__ B0,
                                                 u16* __restrict__ F0,
                                                 const u16* __restrict__ A1,
                                                 const u16* __restrict__ B1,
                                                 u16* __restrict__ F1) {
  __shared__ u16 As[2][128 * 64];   // 32 KB
  __shared__ u16 Bs[2][128 * 64];   // 32 KB
  const u16* A = blockIdx.z ? A1 : A0;
  const u16* B = blockIdx.z ? B1 : B0;
  u16* F = blockIdx.z ? F1 : F0;
  const int t = threadIdx.x;
  const int lane = t & 63, wave = t >> 6;     // 8 waves
  const int l15 = lane & 15, quad = lane >> 4;
  const int mb = blockIdx.y * 128, nb = blockIdx.x * 128;
  const int wm = (wave & 1) * 64;             // M: 2 x 64
  const int wn = (wave >> 1) * 32;            // N: 4 x 32

  const int srow = lane >> 3;                 // 0..7 row within 8-row group
  const int scol = ((lane & 7) ^ srow) * 8;   // xor-swizzled source column

  f32x4 acc[4][2];
#pragma unroll
  for (int i = 0; i < 4; i++)
#pragma unroll
    for (int j = 0; j < 2; j++) acc[i][j] = (f32x4){0.f, 0.f, 0.f, 0.f};

  // prologue: stage kb=0 into buffer 0 (2 A-groups + 2 B-groups per thread)
#pragma unroll
  for (int j = 0; j < 2; j++) {
    const int g = wave * 2 + j;               // 0..15 (8 rows each)
    glds16(A + (size_t)(mb + g * 8 + srow) * 1024 + scol, &As[0][g * 512 + lane * 8]);
    glds16(B + (size_t)(nb + g * 8 + srow) * 1024 + scol, &Bs[0][g * 512 + lane * 8]);
  }

  const int sw = l15 & 7;
  for (int it = 0; it < 16; ++it) {
    __syncthreads();   // drains vmcnt: buf it ready; all waves done with buf it^1
    if (it < 15) {
      const int kb = (it + 1) * 64, bf_ = (it + 1) & 1;
#pragma unroll
      for (int j = 0; j < 2; j++) {
        const int g = wave * 2 + j;
        glds16(A + (size_t)(mb + g * 8 + srow) * 1024 + kb + scol, &As[bf_][g * 512 + lane * 8]);
        glds16(B + (size_t)(nb + g * 8 + srow) * 1024 + kb + scol, &Bs[bf_][g * 512 + lane * 8]);
      }
    }
    const u16* as = As[it & 1];
    const u16* bs = Bs[it & 1];
#pragma unroll
    for (int kk = 0; kk < 2; kk++) {
      const int cb = kk * 4;
      short8 af[4], bfr[2];
#pragma unroll
      for (int mi = 0; mi < 4; mi++)
        af[mi] = *(const short8*)&as[(wm + mi * 16 + l15) * 64 + ((cb + quad) ^ sw) * 8];
#pragma unroll
      for (int ni = 0; ni < 2; ni++)
        bfr[ni] = *(const short8*)&bs[(wn + ni * 16 + l15) * 64 + ((cb + quad) ^ sw) * 8];
#pragma unroll
      for (int mi = 0; mi < 4; mi++)
#pragma unroll
        for (int ni = 0; ni < 2; ni++)
          acc[mi][ni] = __builtin_amdgcn_mfma_f32_16x16x32_bf16(
              af[mi], bfr[ni], acc[mi][ni], 0, 0, 0);
    }
  }

  // epilogue: scatter into fragment layout (C/D: col=l15, row=quad*4+r)
  const int dt_hi = ((wave >> 1) & 1) * 2;    // wn&32 contribution: d = dt*16+l15
#pragma unroll
  for (int mi = 0; mi < 4; mi++) {
#pragma unroll
    for (int r = 0; r < 4; r++) {
      const int row = mb + wm + mi * 16 + quad * 4 + r;   // M index
      const int bt = row >> 9;                             // batch (a or b)
      const int t16 = (row >> 4) & 31;                     // q-tile16
      const int m15 = quad * 4 + r;                        // m within tile
#pragma unroll
      for (int ni = 0; ni < 2; ni++) {
        const int col = nb + wn + ni * 16 + l15;           // N index
        const int h = col >> 6;
        const int dt = dt_hi + ni;                         // 16-col group in d
        const int half = dt >> 1;
        const int quadF = ((dt & 1) << 1) + (l15 >> 3);
        const int j = l15 & 7;
        const size_t idx = ((size_t)((bt * 16 + h) * 32 + t16) << 10)
                         + (half << 9) + (((quadF << 4) + m15) << 3) + j;
        F[idx] = f2bf(acc[mi][ni][r]);
      }
    }
  }
}

// ---- fused QK^T + columnwise LSE over q, mean over a via atomicAdd ----
// No LDS, no barriers: Q/K fragments loaded directly (coalesced lane*16B).
// Each wave owns 64 k-cols (4 tiles); loops 32 q-tiles.
__global__ __launch_bounds__(256) void attn_lse3(const u16* __restrict__ Qf,
                                                 const u16* __restrict__ Kf,
                                                 float* __restrict__ out) {
  const int t = threadIdx.x;
  const int lane = t & 63, wave = t >> 6;
  const int l15 = lane & 15, quad = lane >> 4;
  const int aa = blockIdx.x >> 1, khalf = blockIdx.x & 1;
  const int h = blockIdx.y, b = blockIdx.z;
  const int tt0 = khalf * 16 + wave * 4;      // k-tile16 base (0..31)

  short8 klo[4], khi[4];
#pragma unroll
  for (int tt = 0; tt < 4; tt++) {
    const u16* kp = Kf + (((size_t)(b * 16 + h) * 32 + tt0 + tt) << 10) + lane * 8;
    klo[tt] = *(const short8*)kp;
    khi[tt] = *(const short8*)(kp + 512);
  }

  const u16* qp = Qf + (((size_t)(aa * 16 + h) * 32) << 10) + lane * 8;

  float cs0 = 0.f, cs1 = 0.f, cs2 = 0.f, cs3 = 0.f;
#pragma unroll 4
  for (int qt = 0; qt < 32; ++qt, qp += 1024) {
    short8 alo = *(const short8*)qp;
    short8 ahi = *(const short8*)(qp + 512);
    f32x4 ac0 = (f32x4){0.f, 0.f, 0.f, 0.f};
    f32x4 ac1 = ac0, ac2 = ac0, ac3 = ac0;
    ac0 = __builtin_amdgcn_mfma_f32_16x16x32_bf16(alo, klo[0], ac0, 0, 0, 0);
    ac0 = __builtin_amdgcn_mfma_f32_16x16x32_bf16(ahi, khi[0], ac0, 0, 0, 0);
    ac1 = __builtin_amdgcn_mfma_f32_16x16x32_bf16(alo, klo[1], ac1, 0, 0, 0);
    ac1 = __builtin_amdgcn_mfma_f32_16x16x32_bf16(ahi, khi[1], ac1, 0, 0, 0);
    ac2 = __builtin_amdgcn_mfma_f32_16x16x32_bf16(alo, klo[2], ac2, 0, 0, 0);
    ac2 = __builtin_amdgcn_mfma_f32_16x16x32_bf16(ahi, khi[2], ac2, 0, 0, 0);
    ac3 = __builtin_amdgcn_mfma_f32_16x16x32_bf16(alo, klo[3], ac3, 0, 0, 0);
    ac3 = __builtin_amdgcn_mfma_f32_16x16x32_bf16(ahi, khi[3], ac3, 0, 0, 0);
#pragma unroll
    for (int r = 0; r < 4; r++) {
      cs0 += __builtin_amdgcn_exp2f(ac0[r]);   // bare v_exp_f32
      cs1 += __builtin_amdgcn_exp2f(ac1[r]);
      cs2 += __builtin_amdgcn_exp2f(ac2[r]);
      cs3 += __builtin_amdgcn_exp2f(ac3[r]);
    }
  }
  // finish column sums over the 4 quads (each lane held 4 q-rows per tile)
  cs0 += __shfl_xor(cs0, 16); cs0 += __shfl_xor(cs0, 32);
  cs1 += __shfl_xor(cs1, 16); cs1 += __shfl_xor(cs1, 32);
  cs2 += __shfl_xor(cs2, 16); cs2 += __shfl_xor(cs2, 32);
  cs3 += __shfl_xor(cs3, 16); cs3 += __shfl_xor(cs3, 32);
  const float v = quad == 0 ? cs0 : quad == 1 ? cs1 : quad == 2 ? cs2 : cs3;
  atomicAdd(out + (size_t)b * 8192 + h * 512 + khalf * 256 + wave * 64 + quad * 16 + l15,
            __logf(v));
}

extern "C" void kernel_launch(void* const* d_in, const int* in_sizes, int n_in,
                              void* d_out, int out_size, void* d_ws, size_t ws_size,
                              hipStream_t stream) {
  const float* query  = (const float*)d_in[0];  // [8,512,1024]
  const float* memory = (const float*)d_in[1];  // [8,512,1024]
  const float* wq     = (const float*)d_in[2];  // [1024,1024]
  const float* wk     = (const float*)d_in[3];  // [1024,1024]
  float* out = (float*)d_out;                   // [8,16,512]

  char* ws = (char*)d_ws;
  const size_t MB = 1024 * 1024;
  u16* qb  = (u16*)(ws);             // 8 MB bf16 query
  u16* mb_ = (u16*)(ws + 8  * MB);   // 8 MB bf16 memory
  u16* wqb = (u16*)(ws + 16 * MB);   // 2 MB bf16 W_Q * c
  u16* wkb = (u16*)(ws + 18 * MB);   // 2 MB bf16 W_K
  u16* Qf  = (u16*)(ws + 20 * MB);   // 8 MB Q' in fragment layout
  u16* Kf  = (u16*)(ws + 28 * MB);   // 8 MB K' in fragment layout

  prep<<<10304, 256, 0, stream>>>((const float4*)query, (const float4*)memory,
                                  (const float4*)wq, (const float4*)wk,
                                  (ushort4*)qb, (ushort4*)mb_, (ushort4*)wqb,
                                  (ushort4*)wkb, (float4*)d_out);
  gemm_frag<<<dim3(8, 32, 2), 512, 0, stream>>>(qb, wqb, Qf, mb_, wkb, Kf);
  attn_lse3<<<dim3(16, 16, 8), 256, 0, stream>>>(Qf, Kf, out);
}

// Round 8
// 153.369 us; speedup vs baseline: 1.1185x; 1.1185x over previous
//
#include <hip/hip_runtime.h>
#include <hip/hip_bf16.h>

typedef short short8 __attribute__((ext_vector_type(8)));   // 8 bf16 = 4 VGPRs
typedef float f32x4 __attribute__((ext_vector_type(4)));
typedef unsigned short u16;

__device__ __forceinline__ unsigned short f2bf(float f) {
  unsigned int u = __float_as_uint(f);
  u += 0x7fffu + ((u >> 16) & 1u);    // round-to-nearest-even
  return (unsigned short)(u >> 16);
}

// async 16B global->LDS (dest = wave-uniform base + lane*16)
__device__ __forceinline__ void glds16(const void* g, void* l) {
  __builtin_amdgcn_global_load_lds(
      (const __attribute__((address_space(1))) unsigned int*)g,
      (__attribute__((address_space(3))) unsigned int*)l, 16, 0, 0);
}

// Explicit full drain (vmcnt=0, expcnt=0, lgkmcnt=0) BEFORE s_barrier.
// __syncthreads alone is only a correct fence for global_load_lds staging if
// the compiler emits the vmcnt drain — which is schedule-dependent (r4-r7
// flakiness). Make it explicit.
__device__ __forceinline__ void drain_then_sync() {
  __builtin_amdgcn_s_waitcnt(0);
  __syncthreads();
}

// ---- fused: cast q/m -> bf16, cast wq*(1/(8 ln2)) -> bf16, cast wk, zero out ----
__global__ __launch_bounds__(256) void prep(const float4* __restrict__ q,
                                            const float4* __restrict__ m,
                                            const float4* __restrict__ wq,
                                            const float4* __restrict__ wk,
                                            ushort4* __restrict__ qb,
                                            ushort4* __restrict__ mb,
                                            ushort4* __restrict__ wqb,
                                            ushort4* __restrict__ wkb,
                                            float4* __restrict__ out0) {
  const int i = blockIdx.x * 256 + threadIdx.x;
  const float c = 0.18033688011112042f;  // 1/(8*ln2): folds SCALE and exp->exp2
  if (i < 1048576) {
    float4 v = q[i];
    ushort4 o; o.x = f2bf(v.x); o.y = f2bf(v.y); o.z = f2bf(v.z); o.w = f2bf(v.w);
    qb[i] = o;
  } else if (i < 2097152) {
    float4 v = m[i - 1048576];
    ushort4 o; o.x = f2bf(v.x); o.y = f2bf(v.y); o.z = f2bf(v.z); o.w = f2bf(v.w);
    mb[i - 1048576] = o;
  } else if (i < 2359296) {
    float4 v = wq[i - 2097152];
    ushort4 o; o.x = f2bf(v.x * c); o.y = f2bf(v.y * c); o.z = f2bf(v.z * c); o.w = f2bf(v.w * c);
    wqb[i - 2097152] = o;
  } else if (i < 2621440) {
    float4 v = wk[i - 2359296];
    ushort4 o; o.x = f2bf(v.x); o.y = f2bf(v.y); o.z = f2bf(v.z); o.w = f2bf(v.w);
    wkb[i - 2359296] = o;
  } else if (i < 2637824) {
    out0[i - 2621440] = (float4){0.f, 0.f, 0.f, 0.f};  // zero 65536-float output
  }
}

// ---- C[M,1024] = A[M,1024] @ B[1024,1024]^T, bf16, 128x128 tile, BK=64 ----
// r2's structure (256 thr / 4 waves, glds16, single-buffer 2-barrier K-loop)
// with explicit drains. Grid (64,8): x = mblk*2 + z so XCD = linear%8 pins
// {projection, M-slice set} per XCD (L2 locality experiment, r7-verified
// correctness-neutral).
__global__ __launch_bounds__(256) void gemm_bt2(const u16* __restrict__ A0,
                                                const u16* __restrict__ B0,
                                                u16* __restrict__ C0,
                                                const u16* __restrict__ A1,
                                                const u16* __restrict__ B1,
                                                u16* __restrict__ C1) {
  __shared__ u16 As[128 * 64];
  __shared__ u16 Bs[128 * 64];
  const int zz = blockIdx.x & 1;
  const u16* A = zz ? A1 : A0;
  const u16* B = zz ? B1 : B0;
  u16* C = zz ? C1 : C0;
  const int t = threadIdx.x;
  const int lane = t & 63, wave = t >> 6;
  const int l15 = lane & 15, quad = lane >> 4;
  const int mb = (blockIdx.x >> 1) * 128;   // M-block (32 of them)
  const int nb = blockIdx.y * 128;          // N-block (8 of them)
  const int wm = (wave & 1) * 64, wn = (wave >> 1) * 64;

  const int srow = lane >> 3;                 // 0..7 row within 8-row instr group
  const int scol = ((lane & 7) ^ srow) * 8;   // swizzled source column

  f32x4 acc[4][4];
#pragma unroll
  for (int i = 0; i < 4; i++)
#pragma unroll
    for (int j = 0; j < 4; j++) acc[i][j] = (f32x4){0.f, 0.f, 0.f, 0.f};

  for (int kb = 0; kb < 1024; kb += 64) {
#pragma unroll
    for (int j = 0; j < 4; j++) {
      const int mi_ = wave * 4 + j;           // instr index 0..15
      const int row = mi_ * 8 + srow;
      glds16(A + (size_t)(mb + row) * 1024 + kb + scol, &As[mi_ * 512 + lane * 8]);
      glds16(B + (size_t)(nb + row) * 1024 + kb + scol, &Bs[mi_ * 512 + lane * 8]);
    }
    drain_then_sync();   // explicit vmcnt(0): LDS tiles guaranteed landed
#pragma unroll
    for (int kk = 0; kk < 2; kk++) {
      const int cb = kk * 4;
      const int sw = l15 & 7;
      short8 af[4], bfr[4];
#pragma unroll
      for (int mi = 0; mi < 4; mi++)
        af[mi] = *(const short8*)&As[(wm + mi * 16 + l15) * 64 + ((cb + quad) ^ sw) * 8];
#pragma unroll
      for (int ni = 0; ni < 4; ni++)
        bfr[ni] = *(const short8*)&Bs[(wn + ni * 16 + l15) * 64 + ((cb + quad) ^ sw) * 8];
#pragma unroll
      for (int mi = 0; mi < 4; mi++)
#pragma unroll
        for (int ni = 0; ni < 4; ni++)
          acc[mi][ni] = __builtin_amdgcn_mfma_f32_16x16x32_bf16(
              af[mi], bfr[ni], acc[mi][ni], 0, 0, 0);
    }
    drain_then_sync();   // all reads retired before next iter's fills overwrite
  }
  // epilogue: C/D layout col=l15, row=quad*4+r (r2-verified)
#pragma unroll
  for (int mi = 0; mi < 4; mi++)
#pragma unroll
    for (int r = 0; r < 4; r++) {
      const int row = mb + wm + mi * 16 + quad * 4 + r;
      const size_t base = (size_t)row * 1024 + nb + wn;
#pragma unroll
      for (int ni = 0; ni < 4; ni++)
        C[base + ni * 16 + l15] = f2bf(acc[mi][ni][r]);
    }
}

// ---- fused QK^T + columnwise LSE, atomicAdd combine over a ----
// r3's structure with explicit drain before the dbuf barrier.
__global__ __launch_bounds__(256) void attn_lse2(const u16* __restrict__ Qp,
                                                 const u16* __restrict__ Kp,
                                                 float* __restrict__ out) {
  __shared__ u16 qs[2][64 * 64];   // 16 KB double-buffered
  const int t = threadIdx.x;
  const int lane = t & 63, wave = t >> 6;
  const int l15 = lane & 15, quad = lane >> 4;
  const int kt = blockIdx.x & 1, aa = blockIdx.x >> 1;
  const int h = blockIdx.y, b = blockIdx.z;
  const int kwave = kt * 256 + wave * 64;

  // K fragments for 4 k-tiles x (d-lo, d-hi), in registers throughout
  short8 klo[4], khi[4];
#pragma unroll
  for (int tt = 0; tt < 4; tt++) {
    const short8* kg = (const short8*)(Kp + (size_t)(b * 512 + kwave + tt * 16 + l15) * 1024
                                       + h * 64 + quad * 8);
    klo[tt] = kg[0];
    khi[tt] = kg[4];   // +32 elements
  }

  const int srow = lane >> 3;
  const int scol = ((lane & 7) ^ srow) * 8;
  const u16* qbase = Qp + (size_t)(aa * 512) * 1024 + h * 64;

  // loop-invariant swizzled LDS read columns (in u16 elements)
  const int sw = l15 & 7;
  const int colLo = (quad ^ sw) * 8;
  const int colHi = ((4 + quad) ^ sw) * 8;
  const int rrow = l15 * 64;   // qt adds a compile-time 16*64 stride

  float cs0 = 0.f, cs1 = 0.f, cs2 = 0.f, cs3 = 0.f;

  // prologue: stage tile 0
#pragma unroll
  for (int j = 0; j < 2; j++) {
    const int mi_ = wave * 2 + j;
    glds16(qbase + (size_t)(mi_ * 8 + srow) * 1024 + scol, &qs[0][mi_ * 512 + lane * 8]);
  }

  for (int i = 0; i < 8; i++) {
    drain_then_sync();   // my tile-i fills landed; all waves' tile-(i-1) reads retired
    if (i < 7) {
#pragma unroll
      for (int j = 0; j < 2; j++) {
        const int mi_ = wave * 2 + j;
        glds16(qbase + (size_t)((i + 1) * 64 + mi_ * 8 + srow) * 1024 + scol,
               &qs[(i + 1) & 1][mi_ * 512 + lane * 8]);
      }
    }
    const u16* buf = qs[i & 1];
#pragma unroll
    for (int qt = 0; qt < 4; qt++) {
      short8 alo = *(const short8*)&buf[qt * 1024 + rrow + colLo];
      short8 ahi = *(const short8*)&buf[qt * 1024 + rrow + colHi];
      f32x4 ac0 = (f32x4){0.f, 0.f, 0.f, 0.f};
      f32x4 ac1 = ac0, ac2 = ac0, ac3 = ac0;
      ac0 = __builtin_amdgcn_mfma_f32_16x16x32_bf16(alo, klo[0], ac0, 0, 0, 0);
      ac0 = __builtin_amdgcn_mfma_f32_16x16x32_bf16(ahi, khi[0], ac0, 0, 0, 0);
      ac1 = __builtin_amdgcn_mfma_f32_16x16x32_bf16(alo, klo[1], ac1, 0, 0, 0);
      ac1 = __builtin_amdgcn_mfma_f32_16x16x32_bf16(ahi, khi[1], ac1, 0, 0, 0);
      ac2 = __builtin_amdgcn_mfma_f32_16x16x32_bf16(alo, klo[2], ac2, 0, 0, 0);
      ac2 = __builtin_amdgcn_mfma_f32_16x16x32_bf16(ahi, khi[2], ac2, 0, 0, 0);
      ac3 = __builtin_amdgcn_mfma_f32_16x16x32_bf16(alo, klo[3], ac3, 0, 0, 0);
      ac3 = __builtin_amdgcn_mfma_f32_16x16x32_bf16(ahi, khi[3], ac3, 0, 0, 0);
#pragma unroll
      for (int r = 0; r < 4; r++) {
        cs0 += __builtin_amdgcn_exp2f(ac0[r]);   // bare v_exp_f32
        cs1 += __builtin_amdgcn_exp2f(ac1[r]);
        cs2 += __builtin_amdgcn_exp2f(ac2[r]);
        cs3 += __builtin_amdgcn_exp2f(ac3[r]);
      }
    }
  }
  // finish column sums over the 4 quads
  cs0 += __shfl_xor(cs0, 16); cs0 += __shfl_xor(cs0, 32);
  cs1 += __shfl_xor(cs1, 16); cs1 += __shfl_xor(cs1, 32);
  cs2 += __shfl_xor(cs2, 16); cs2 += __shfl_xor(cs2, 32);
  cs3 += __shfl_xor(cs3, 16); cs3 += __shfl_xor(cs3, 32);
  const float v = quad == 0 ? cs0 : quad == 1 ? cs1 : quad == 2 ? cs2 : cs3;
  atomicAdd(out + (size_t)b * 8192 + h * 512 + kwave + quad * 16 + l15, __logf(v));
}

extern "C" void kernel_launch(void* const* d_in, const int* in_sizes, int n_in,
                              void* d_out, int out_size, void* d_ws, size_t ws_size,
                              hipStream_t stream) {
  const float* query  = (const float*)d_in[0];  // [8,512,1024]
  const float* memory = (const float*)d_in[1];  // [8,512,1024]
  const float* wq     = (const float*)d_in[2];  // [1024,1024]
  const float* wk     = (const float*)d_in[3];  // [1024,1024]
  float* out = (float*)d_out;                   // [8,16,512]

  char* ws = (char*)d_ws;
  const size_t MB = 1024 * 1024;
  u16* qb  = (u16*)(ws);             // 8 MB bf16 query
  u16* mb_ = (u16*)(ws + 8  * MB);   // 8 MB bf16 memory
  u16* wqb = (u16*)(ws + 16 * MB);   // 2 MB bf16 W_Q * c
  u16* wkb = (u16*)(ws + 18 * MB);   // 2 MB bf16 W_K
  u16* Qp  = (u16*)(ws + 20 * MB);   // 8 MB projected Q'
  u16* Kp  = (u16*)(ws + 28 * MB);   // 8 MB projected K

  prep<<<10304, 256, 0, stream>>>((const float4*)query, (const float4*)memory,
                                  (const float4*)wq, (const float4*)wk,
                                  (ushort4*)qb, (ushort4*)mb_, (ushort4*)wqb,
                                  (ushort4*)wkb, (float4*)d_out);
  gemm_bt2<<<dim3(64, 8), 256, 0, stream>>>(qb, wqb, Qp, mb_, wkb, Kp);
  attn_lse2<<<dim3(16, 16, 8), 256, 0, stream>>>(Qp, Kp, out);
}

// Round 9
// 145.555 us; speedup vs baseline: 1.1786x; 1.0537x over previous
//
#include <hip/hip_runtime.h>
#include <hip/hip_bf16.h>

typedef short short8 __attribute__((ext_vector_type(8)));   // 8 bf16 = 4 VGPRs
typedef float f32x4 __attribute__((ext_vector_type(4)));
typedef unsigned short u16;

__device__ __forceinline__ unsigned short f2bf(float f) {
  unsigned int u = __float_as_uint(f);
  u += 0x7fffu + ((u >> 16) & 1u);    // round-to-nearest-even
  return (unsigned short)(u >> 16);
}

// async 16B global->LDS (dest = wave-uniform base + lane*16)
__device__ __forceinline__ void glds16(const void* g, void* l) {
  __builtin_amdgcn_global_load_lds(
      (const __attribute__((address_space(1))) unsigned int*)g,
      (__attribute__((address_space(3))) unsigned int*)l, 16, 0, 0);
}

// Explicit full drain (vmcnt=0, expcnt=0, lgkmcnt=0) BEFORE s_barrier.
// __syncthreads alone is NOT a reliable fence for global_load_lds staging
// (r4-r7 flakiness; r8 passed with this). The drain retires this wave's async
// fills (vmcnt) AND its LDS reads (lgkmcnt), making 1-barrier double-buffer
// provably race-free.
__device__ __forceinline__ void drain_then_sync() {
  __builtin_amdgcn_s_waitcnt(0);
  __syncthreads();
}

// ---- fused: cast q/m -> bf16, cast wq*(1/(8 ln2)) -> bf16, cast wk, zero out ----
__global__ __launch_bounds__(256) void prep(const float4* __restrict__ q,
                                            const float4* __restrict__ m,
                                            const float4* __restrict__ wq,
                                            const float4* __restrict__ wk,
                                            ushort4* __restrict__ qb,
                                            ushort4* __restrict__ mb,
                                            ushort4* __restrict__ wqb,
                                            ushort4* __restrict__ wkb,
                                            float4* __restrict__ out0) {
  const int i = blockIdx.x * 256 + threadIdx.x;
  const float c = 0.18033688011112042f;  // 1/(8*ln2): folds SCALE and exp->exp2
  if (i < 1048576) {
    float4 v = q[i];
    ushort4 o; o.x = f2bf(v.x); o.y = f2bf(v.y); o.z = f2bf(v.z); o.w = f2bf(v.w);
    qb[i] = o;
  } else if (i < 2097152) {
    float4 v = m[i - 1048576];
    ushort4 o; o.x = f2bf(v.x); o.y = f2bf(v.y); o.z = f2bf(v.z); o.w = f2bf(v.w);
    mb[i - 1048576] = o;
  } else if (i < 2359296) {
    float4 v = wq[i - 2097152];
    ushort4 o; o.x = f2bf(v.x * c); o.y = f2bf(v.y * c); o.z = f2bf(v.z * c); o.w = f2bf(v.w * c);
    wqb[i - 2097152] = o;
  } else if (i < 2621440) {
    float4 v = wk[i - 2359296];
    ushort4 o; o.x = f2bf(v.x); o.y = f2bf(v.y); o.z = f2bf(v.z); o.w = f2bf(v.w);
    wkb[i - 2359296] = o;
  } else if (i < 2637824) {
    out0[i - 2621440] = (float4){0.f, 0.f, 0.f, 0.f};  // zero 65536-float output
  }
}

// ---- C = A[M,1024] @ B[N,1024]^T, 128x128 tile, BK=64, 512 thr (8 waves),
// double-buffered LDS, ONE drain+barrier per iter: prefetch of tile k+1
// overlaps compute of tile k. Race-free via drain_then_sync (r8 evidence).
// Grid (64,8): x = mblk*2 + z -> XCD = linear%8 pins {projection, M-slices}
// per XCD (r8 mapping). Epilogue: r2-verified row-major C/D mapping.
__global__ __launch_bounds__(512) void gemm_db(const u16* __restrict__ A0,
                                               const u16* __restrict__ B0,
                                               u16* __restrict__ C0,
                                               const u16* __restrict__ A1,
                                               const u16* __restrict__ B1,
                                               u16* __restrict__ C1) {
  __shared__ u16 As[2][128 * 64];   // 32 KB
  __shared__ u16 Bs[2][128 * 64];   // 32 KB
  const int zz = blockIdx.x & 1;
  const u16* A = zz ? A1 : A0;
  const u16* B = zz ? B1 : B0;
  u16* C = zz ? C1 : C0;
  const int t = threadIdx.x;
  const int lane = t & 63, wave = t >> 6;     // 8 waves
  const int l15 = lane & 15, quad = lane >> 4;
  const int mb = (blockIdx.x >> 1) * 128;     // M-block (32 of them)
  const int nb = blockIdx.y * 128;            // N-block (8 of them)
  const int wm = (wave & 1) * 64;             // M: 2 x 64
  const int wn = (wave >> 1) * 32;            // N: 4 x 32

  const int srow = lane >> 3;                 // 0..7 row within 8-row group
  const int scol = ((lane & 7) ^ srow) * 8;   // xor-swizzled source column
  const int sw = l15 & 7;

  f32x4 acc[4][2];
#pragma unroll
  for (int i = 0; i < 4; i++)
#pragma unroll
    for (int j = 0; j < 2; j++) acc[i][j] = (f32x4){0.f, 0.f, 0.f, 0.f};

  // prologue: stage kb=0 into buffer 0 (2 A-groups + 2 B-groups per thread)
#pragma unroll
  for (int j = 0; j < 2; j++) {
    const int g = wave * 2 + j;               // 0..15 (8 rows each)
    glds16(A + (size_t)(mb + g * 8 + srow) * 1024 + scol, &As[0][g * 512 + lane * 8]);
    glds16(B + (size_t)(nb + g * 8 + srow) * 1024 + scol, &Bs[0][g * 512 + lane * 8]);
  }

  for (int it = 0; it < 16; ++it) {
    drain_then_sync();  // my buf[it] fills landed; all waves' buf[it^1] reads retired
    if (it < 15) {
      const int kb = (it + 1) * 64, bf_ = (it + 1) & 1;
#pragma unroll
      for (int j = 0; j < 2; j++) {
        const int g = wave * 2 + j;
        glds16(A + (size_t)(mb + g * 8 + srow) * 1024 + kb + scol, &As[bf_][g * 512 + lane * 8]);
        glds16(B + (size_t)(nb + g * 8 + srow) * 1024 + kb + scol, &Bs[bf_][g * 512 + lane * 8]);
      }
    }
    const u16* as = As[it & 1];
    const u16* bs = Bs[it & 1];
#pragma unroll
    for (int kk = 0; kk < 2; kk++) {
      const int cb = kk * 4;
      short8 af[4], bfr[2];
#pragma unroll
      for (int mi = 0; mi < 4; mi++)
        af[mi] = *(const short8*)&as[(wm + mi * 16 + l15) * 64 + ((cb + quad) ^ sw) * 8];
#pragma unroll
      for (int ni = 0; ni < 2; ni++)
        bfr[ni] = *(const short8*)&bs[(wn + ni * 16 + l15) * 64 + ((cb + quad) ^ sw) * 8];
#pragma unroll
      for (int mi = 0; mi < 4; mi++)
#pragma unroll
        for (int ni = 0; ni < 2; ni++)
          acc[mi][ni] = __builtin_amdgcn_mfma_f32_16x16x32_bf16(
              af[mi], bfr[ni], acc[mi][ni], 0, 0, 0);
    }
  }

  // epilogue: C/D layout col=l15, row=quad*4+r (r2-verified)
#pragma unroll
  for (int mi = 0; mi < 4; mi++)
#pragma unroll
    for (int r = 0; r < 4; r++) {
      const int row = mb + wm + mi * 16 + quad * 4 + r;
      const size_t base = (size_t)row * 1024 + nb + wn;
#pragma unroll
      for (int ni = 0; ni < 2; ni++)
        C[base + ni * 16 + l15] = f2bf(acc[mi][ni][r]);
    }
}

// ---- fused QK^T + columnwise LSE, atomicAdd combine over a (r8 verbatim) ----
__global__ __launch_bounds__(256) void attn_lse2(const u16* __restrict__ Qp,
                                                 const u16* __restrict__ Kp,
                                                 float* __restrict__ out) {
  __shared__ u16 qs[2][64 * 64];   // 16 KB double-buffered
  const int t = threadIdx.x;
  const int lane = t & 63, wave = t >> 6;
  const int l15 = lane & 15, quad = lane >> 4;
  const int kt = blockIdx.x & 1, aa = blockIdx.x >> 1;
  const int h = blockIdx.y, b = blockIdx.z;
  const int kwave = kt * 256 + wave * 64;

  // K fragments for 4 k-tiles x (d-lo, d-hi), in registers throughout
  short8 klo[4], khi[4];
#pragma unroll
  for (int tt = 0; tt < 4; tt++) {
    const short8* kg = (const short8*)(Kp + (size_t)(b * 512 + kwave + tt * 16 + l15) * 1024
                                       + h * 64 + quad * 8);
    klo[tt] = kg[0];
    khi[tt] = kg[4];   // +32 elements
  }

  const int srow = lane >> 3;
  const int scol = ((lane & 7) ^ srow) * 8;
  const u16* qbase = Qp + (size_t)(aa * 512) * 1024 + h * 64;

  // loop-invariant swizzled LDS read columns (in u16 elements)
  const int sw = l15 & 7;
  const int colLo = (quad ^ sw) * 8;
  const int colHi = ((4 + quad) ^ sw) * 8;
  const int rrow = l15 * 64;   // qt adds a compile-time 16*64 stride

  float cs0 = 0.f, cs1 = 0.f, cs2 = 0.f, cs3 = 0.f;

  // prologue: stage tile 0
#pragma unroll
  for (int j = 0; j < 2; j++) {
    const int mi_ = wave * 2 + j;
    glds16(qbase + (size_t)(mi_ * 8 + srow) * 1024 + scol, &qs[0][mi_ * 512 + lane * 8]);
  }

  for (int i = 0; i < 8; i++) {
    drain_then_sync();   // my tile-i fills landed; all waves' tile-(i-1) reads retired
    if (i < 7) {
#pragma unroll
      for (int j = 0; j < 2; j++) {
        const int mi_ = wave * 2 + j;
        glds16(qbase + (size_t)((i + 1) * 64 + mi_ * 8 + srow) * 1024 + scol,
               &qs[(i + 1) & 1][mi_ * 512 + lane * 8]);
      }
    }
    const u16* buf = qs[i & 1];
#pragma unroll
    for (int qt = 0; qt < 4; qt++) {
      short8 alo = *(const short8*)&buf[qt * 1024 + rrow + colLo];
      short8 ahi = *(const short8*)&buf[qt * 1024 + rrow + colHi];
      f32x4 ac0 = (f32x4){0.f, 0.f, 0.f, 0.f};
      f32x4 ac1 = ac0, ac2 = ac0, ac3 = ac0;
      ac0 = __builtin_amdgcn_mfma_f32_16x16x32_bf16(alo, klo[0], ac0, 0, 0, 0);
      ac0 = __builtin_amdgcn_mfma_f32_16x16x32_bf16(ahi, khi[0], ac0, 0, 0, 0);
      ac1 = __builtin_amdgcn_mfma_f32_16x16x32_bf16(alo, klo[1], ac1, 0, 0, 0);
      ac1 = __builtin_amdgcn_mfma_f32_16x16x32_bf16(ahi, khi[1], ac1, 0, 0, 0);
      ac2 = __builtin_amdgcn_mfma_f32_16x16x32_bf16(alo, klo[2], ac2, 0, 0, 0);
      ac2 = __builtin_amdgcn_mfma_f32_16x16x32_bf16(ahi, khi[2], ac2, 0, 0, 0);
      ac3 = __builtin_amdgcn_mfma_f32_16x16x32_bf16(alo, klo[3], ac3, 0, 0, 0);
      ac3 = __builtin_amdgcn_mfma_f32_16x16x32_bf16(ahi, khi[3], ac3, 0, 0, 0);
#pragma unroll
      for (int r = 0; r < 4; r++) {
        cs0 += __builtin_amdgcn_exp2f(ac0[r]);   // bare v_exp_f32
        cs1 += __builtin_amdgcn_exp2f(ac1[r]);
        cs2 += __builtin_amdgcn_exp2f(ac2[r]);
        cs3 += __builtin_amdgcn_exp2f(ac3[r]);
      }
    }
  }
  // finish column sums over the 4 quads
  cs0 += __shfl_xor(cs0, 16); cs0 += __shfl_xor(cs0, 32);
  cs1 += __shfl_xor(cs1, 16); cs1 += __shfl_xor(cs1, 32);
  cs2 += __shfl_xor(cs2, 16); cs2 += __shfl_xor(cs2, 32);
  cs3 += __shfl_xor(cs3, 16); cs3 += __shfl_xor(cs3, 32);
  const float v = quad == 0 ? cs0 : quad == 1 ? cs1 : quad == 2 ? cs2 : cs3;
  atomicAdd(out + (size_t)b * 8192 + h * 512 + kwave + quad * 16 + l15, __logf(v));
}

extern "C" void kernel_launch(void* const* d_in, const int* in_sizes, int n_in,
                              void* d_out, int out_size, void* d_ws, size_t ws_size,
                              hipStream_t stream) {
  const float* query  = (const float*)d_in[0];  // [8,512,1024]
  const float* memory = (const float*)d_in[1];  // [8,512,1024]
  const float* wq     = (const float*)d_in[2];  // [1024,1024]
  const float* wk     = (const float*)d_in[3];  // [1024,1024]
  float* out = (float*)d_out;                   // [8,16,512]

  char* ws = (char*)d_ws;
  const size_t MB = 1024 * 1024;
  u16* qb  = (u16*)(ws);             // 8 MB bf16 query
  u16* mb_ = (u16*)(ws + 8  * MB);   // 8 MB bf16 memory
  u16* wqb = (u16*)(ws + 16 * MB);   // 2 MB bf16 W_Q * c
  u16* wkb = (u16*)(ws + 18 * MB);   // 2 MB bf16 W_K
  u16* Qp  = (u16*)(ws + 20 * MB);   // 8 MB projected Q'
  u16* Kp  = (u16*)(ws + 28 * MB);   // 8 MB projected K

  prep<<<10304, 256, 0, stream>>>((const float4*)query, (const float4*)memory,
                                  (const float4*)wq, (const float4*)wk,
                                  (ushort4*)qb, (ushort4*)mb_, (ushort4*)wqb,
                                  (ushort4*)wkb, (float4*)d_out);
  gemm_db<<<dim3(64, 8), 512, 0, stream>>>(qb, wqb, Qp, mb_, wkb, Kp);
  attn_lse2<<<dim3(16, 16, 8), 256, 0, stream>>>(Qp, Kp, out);
}